// Round 2
// baseline (521.393 us; speedup 1.0000x reference)
//
#include <hip/hip_runtime.h>

// WeightedLoss: loss_i = (target_i == 1) ? 1 - sigmoid(pred_i) : 0.1 ; out = mean(loss)
// 1 - sigmoid(x) = 1 / (1 + exp(x))
//
// R11: two-pass stream separation (R10 structure), double-count bug fixed.
//   R10 failed with absmax 4.88e-2 == 0.1 * frac(t!=1): pass 1 counted the 0.1
//   term AND pass 2's pproc returned 0.1 for unmasked elements. Fix: pproc
//   returns 0.0 for unmasked; the 0.1 term is owned solely by pass 1's exact
//   integer count.
//   Theory under test (unchanged): offset-matched dual read streams cause DRAM
//   row ping-pong ~halving read efficiency (fills hit 6.6 TB/s, fused kernel
//   plateaus at ~3.4 TB/s). Pass 1 reads ONLY target -> 1 bit/elem ballot mask
//   (8 MiB in d_ws) + 0.1*count(t!=1). Pass 2 reads ONLY pred (+ L2-resident
//   mask, wave-uniform 16B broadcast loads) -> sigmoid term.
// Prediction: absmax ~0; kernel ~157us -> ~90-100us; dur_us 482.8 -> ~410-425.
// Fallbacks: R9 fused kernel if ws too small; generic for unaligned n.

#define BLOCK 256
#define GRID  2048   // 8 blocks/CU

typedef float vf4 __attribute__((ext_vector_type(4)));
typedef int   vi4 __attribute__((ext_vector_type(4)));
typedef unsigned long long u64;
typedef u64 vu2 __attribute__((ext_vector_type(2)));

__device__ __forceinline__ float loss4(vf4 p, vi4 t) {
    float l0 = (t.x == 1) ? 1.0f / (1.0f + __expf(p.x)) : 0.1f;
    float l1 = (t.y == 1) ? 1.0f / (1.0f + __expf(p.y)) : 0.1f;
    float l2 = (t.z == 1) ? 1.0f / (1.0f + __expf(p.z)) : 0.1f;
    float l3 = (t.w == 1) ? 1.0f / (1.0f + __expf(p.w)) : 0.1f;
    return (l0 + l1) + (l2 + l3);
}

__device__ __forceinline__ void block_reduce_atomic(float acc, float scale,
                                                    float* __restrict__ out) {
#pragma unroll
    for (int off = 32; off > 0; off >>= 1)
        acc += __shfl_down(acc, off, 64);
    __shared__ float smem[BLOCK / 64];
    const int lane = threadIdx.x & 63;
    const int wave = threadIdx.x >> 6;
    if (lane == 0) smem[wave] = acc;
    __syncthreads();
    if (threadIdx.x == 0) {
        float bsum = (smem[0] + smem[1]) + (smem[2] + smem[3]);
        atomicAdd(out, bsum * scale);
    }
}

// ---------------- Pass 1: target stream -> ballot bitmask ----------------
// chunk c (one wave-iteration) covers elements [c*256, c*256+256): lane l,
// slot j holds element c*256 + 4*l + j. Ballot j stored at mask[c*4 + j];
// bit l of that word = (target[c*256 + 4*l + j] == 1).
__device__ __forceinline__ void tproc(vi4 t, int chunk, int lane,
                                      u64* __restrict__ mask, int& cnt0) {
    u64 b0 = __ballot(t.x == 1);
    u64 b1 = __ballot(t.y == 1);
    u64 b2 = __ballot(t.z == 1);
    u64 b3 = __ballot(t.w == 1);
    cnt0 += (t.x != 1) + (t.y != 1) + (t.z != 1) + (t.w != 1);
    if (lane < 4) {
        u64 b = (lane == 0) ? b0 : (lane == 1) ? b1 : (lane == 2) ? b2 : b3;
        mask[(size_t)chunk * 4 + lane] = b;   // 32B per wave, coalesced
    }
}

__global__ __launch_bounds__(BLOCK)
void tgt_mask(const vi4* __restrict__ t4, u64* __restrict__ mask,
              float* __restrict__ out, int iters, int stride, float inv_n) {
    const int tid  = threadIdx.x;
    const int lane = tid & 63;
    const int wv   = tid >> 6;
    const int cstep = stride >> 6;               // wave-chunks per grid sweep

    int i     = blockIdx.x * BLOCK + tid;
    int chunk = blockIdx.x * (BLOCK / 64) + wv;

    vi4 tA = __builtin_nontemporal_load(&t4[i]);
    vi4 tB = __builtin_nontemporal_load(&t4[i + stride]);
    int idx = i + 2 * stride;

    int cnt0 = 0;
    for (int k = 0; k < iters - 2; ++k) {
        vi4 tN = __builtin_nontemporal_load(&t4[idx]);
        idx += stride;
        tproc(tA, chunk, lane, mask, cnt0);
        chunk += cstep;
        tA = tB; tB = tN;
    }
    tproc(tA, chunk, lane, mask, cnt0); chunk += cstep;
    tproc(tB, chunk, lane, mask, cnt0);

    block_reduce_atomic(0.1f * (float)cnt0, inv_n, out);
}

// ---------------- Pass 2: pred stream + bitmask -> sigmoid term ----------------
// NOTE: unmasked elements contribute 0.0 here — their 0.1 term was already
// added (exactly, via integer count) by pass 1. (R10 bug: returned 0.1 here.)
__device__ __forceinline__ float pproc(vf4 p, const u64* __restrict__ mp, int lane) {
    vu2 m01 = *(const vu2*)(mp);       // wave-uniform 16B load (broadcast)
    vu2 m23 = *(const vu2*)(mp + 2);
    float l0 = ((m01.x >> lane) & 1ull) ? 1.0f / (1.0f + __expf(p.x)) : 0.0f;
    float l1 = ((m01.y >> lane) & 1ull) ? 1.0f / (1.0f + __expf(p.y)) : 0.0f;
    float l2 = ((m23.x >> lane) & 1ull) ? 1.0f / (1.0f + __expf(p.z)) : 0.0f;
    float l3 = ((m23.y >> lane) & 1ull) ? 1.0f / (1.0f + __expf(p.w)) : 0.0f;
    return (l0 + l1) + (l2 + l3);
}

__global__ __launch_bounds__(BLOCK)
void pred_loss(const vf4* __restrict__ p4, const u64* __restrict__ mask,
               float* __restrict__ out, int iters, int stride, float inv_n) {
    const int tid  = threadIdx.x;
    const int lane = tid & 63;
    const int wv   = tid >> 6;
    const int cstep = stride >> 6;

    int i     = blockIdx.x * BLOCK + tid;
    int chunk = blockIdx.x * (BLOCK / 64) + wv;

    vf4 pA = __builtin_nontemporal_load(&p4[i]);
    vf4 pB = __builtin_nontemporal_load(&p4[i + stride]);
    int idx = i + 2 * stride;

    float acc = 0.0f;
    for (int k = 0; k < iters - 2; ++k) {
        vf4 pN = __builtin_nontemporal_load(&p4[idx]);
        idx += stride;
        acc += pproc(pA, mask + (size_t)chunk * 4, lane);
        chunk += cstep;
        pA = pB; pB = pN;
    }
    acc += pproc(pA, mask + (size_t)chunk * 4, lane); chunk += cstep;
    acc += pproc(pB, mask + (size_t)chunk * 4, lane);

    block_reduce_atomic(acc, inv_n, out);
}

// ---------------- Fallback: R9 fused two-stream kernel ----------------
__global__ __launch_bounds__(BLOCK)
void wloss_nt(const vf4* __restrict__ p4,
              const vi4* __restrict__ t4,
              float* __restrict__ out,
              int iters, int stride, float inv_n) {
    int i = blockIdx.x * BLOCK + threadIdx.x;

    vf4 pA = __builtin_nontemporal_load(&p4[i]);
    vi4 tA = __builtin_nontemporal_load(&t4[i]);
    vf4 pB = __builtin_nontemporal_load(&p4[i + stride]);
    vi4 tB = __builtin_nontemporal_load(&t4[i + stride]);
    int idx = i + 2 * stride;

    float acc = 0.0f;
    for (int k = 0; k < iters - 2; ++k) {
        vf4 pN = __builtin_nontemporal_load(&p4[idx]);
        vi4 tN = __builtin_nontemporal_load(&t4[idx]);
        idx += stride;
        acc += loss4(pA, tA);
        pA = pB; tA = tB;
        pB = pN; tB = tN;
    }
    acc += loss4(pA, tA);
    acc += loss4(pB, tB);

    block_reduce_atomic(acc, inv_n, out);
}

// ---------------- Generic fallback for arbitrary n ----------------
__global__ __launch_bounds__(BLOCK)
void wloss_generic(const float* __restrict__ pred,
                   const int*   __restrict__ tgt,
                   float* __restrict__ out,
                   long long n, float inv_n) {
    const long long n4     = n >> 2;
    const long long tid    = (long long)blockIdx.x * blockDim.x + threadIdx.x;
    const long long stride = (long long)gridDim.x * blockDim.x;

    const vf4* p4 = (const vf4*)pred;
    const vi4* t4 = (const vi4*)tgt;

    float acc = 0.0f;
    for (long long i = tid; i < n4; i += stride)
        acc += loss4(p4[i], t4[i]);
    if (blockIdx.x == 0) {
        for (long long i = (n4 << 2) + threadIdx.x; i < n; i += blockDim.x)
            acc += (tgt[i] == 1) ? 1.0f / (1.0f + __expf(pred[i])) : 0.1f;
    }
    block_reduce_atomic(acc, inv_n, out);
}

extern "C" void kernel_launch(void* const* d_in, const int* in_sizes, int n_in,
                              void* d_out, int out_size, void* d_ws, size_t ws_size,
                              hipStream_t stream) {
    const float* pred = (const float*)d_in[0];
    const int*   tgt  = (const int*)d_in[1];
    float*       out  = (float*)d_out;

    const long long n = (long long)in_sizes[0];
    const float inv_n = 1.0f / (float)n;

    hipMemsetAsync(out, 0, sizeof(float), stream);

    const long long n4 = n >> 2;
    const long long stride = (long long)GRID * BLOCK;   // 2^19 float4/step
    const bool tiled = ((n & 3) == 0) && (n4 % stride == 0) && (n4 / stride >= 3);
    const size_t mask_bytes = (size_t)(n >> 3);         // 1 bit/elem: n/8 bytes

    if (tiled && d_ws != nullptr && ws_size >= mask_bytes) {
        const int iters = (int)(n4 / stride);           // 32 for N=2^26
        u64* mask = (u64*)d_ws;
        tgt_mask <<<GRID, BLOCK, 0, stream>>>((const vi4*)tgt, mask, out,
                                              iters, (int)stride, inv_n);
        pred_loss<<<GRID, BLOCK, 0, stream>>>((const vf4*)pred, mask, out,
                                              iters, (int)stride, inv_n);
    } else if (tiled) {
        const int iters = (int)(n4 / stride);
        wloss_nt<<<GRID, BLOCK, 0, stream>>>((const vf4*)pred,
                                             (const vi4*)tgt, out,
                                             iters, (int)stride, inv_n);
    } else {
        long long g = (n4 + BLOCK - 1) / BLOCK;
        if (g > 8192) g = 8192;
        if (g < 1)    g = 1;
        wloss_generic<<<(int)g, BLOCK, 0, stream>>>(pred, tgt, out, n, inv_n);
    }
}